// Round 9
// baseline (8093.479 us; speedup 1.0000x reference)
//
#include <hip/hip_runtime.h>

constexpr int kDepth = 6;
constexpr int kB = 8;
constexpr int kN = 1024;
constexpr int kDim = 768;
constexpr int kH = 12;
constexpr int kDh = 64;
constexpr int kMlp = 3072;
constexpr int kRows = kB * kN;   // 8192
constexpr int kQKV = 2304;       // q(768) k(768) v(768)

typedef __attribute__((ext_vector_type(4))) float f32x4;
typedef __attribute__((ext_vector_type(8))) short bf16x8;

__device__ __forceinline__ f32x4 mfma16x16x32(bf16x8 a, bf16x8 b, f32x4 c) {
  return __builtin_amdgcn_mfma_f32_16x16x32_bf16(a, b, c, 0, 0, 0);
}

__device__ __forceinline__ unsigned short f2bf(float f) {
  unsigned int u = __builtin_bit_cast(unsigned int, f);
  u = u + 0x7FFFu + ((u >> 16) & 1u);
  return (unsigned short)(u >> 16);
}

__device__ __forceinline__ float bf2f(unsigned short u) {
  return __builtin_bit_cast(float, (unsigned int)u << 16);
}

__device__ __forceinline__ void gload_lds16(const void* g, void* l) {
  __builtin_amdgcn_global_load_lds((__attribute__((address_space(1))) void*)g,
                                   (__attribute__((address_space(3))) void*)l,
                                   16, 0, 0);
}

// ---------------- LayerNorm: f32 in -> bf16 out ----------------
__global__ __launch_bounds__(256) void ln_kernel(const float* __restrict__ x,
                                                 const float* __restrict__ gamma,
                                                 const float* __restrict__ beta,
                                                 unsigned short* __restrict__ out) {
  int row = blockIdx.x, tid = threadIdx.x;
  const float* xr = x + (size_t)row * kDim;
  float v0 = xr[tid], v1 = xr[tid + 256], v2 = xr[tid + 512];
  float s = v0 + v1 + v2;
  float q = v0 * v0 + v1 * v1 + v2 * v2;
#pragma unroll
  for (int o = 32; o >= 1; o >>= 1) {
    s += __shfl_xor(s, o);
    q += __shfl_xor(q, o);
  }
  __shared__ float ss[4], sq[4];
  int wid = tid >> 6, lane = tid & 63;
  if (lane == 0) { ss[wid] = s; sq[wid] = q; }
  __syncthreads();
  s = ss[0] + ss[1] + ss[2] + ss[3];
  q = sq[0] + sq[1] + sq[2] + sq[3];
  float mean = s * (1.0f / kDim);
  float var = q * (1.0f / kDim) - mean * mean;
  float rstd = rsqrtf(var + 1e-5f);
  unsigned short* orow = out + (size_t)row * kDim;
  orow[tid]       = f2bf((v0 - mean) * rstd * gamma[tid]       + beta[tid]);
  orow[tid + 256] = f2bf((v1 - mean) * rstd * gamma[tid + 256] + beta[tid + 256]);
  orow[tid + 512] = f2bf((v2 - mean) * rstd * gamma[tid + 512] + beta[tid + 512]);
}

// ---------------- Batched weight transpose: all 5 matrices of one layer ----------------
__global__ __launch_bounds__(256) void transpose_all(const float* __restrict__ Wq,
                                                     const float* __restrict__ Wkv,
                                                     const float* __restrict__ Wo,
                                                     const float* __restrict__ W1,
                                                     const float* __restrict__ W2,
                                                     unsigned short* __restrict__ wqkvT,
                                                     unsigned short* __restrict__ woT,
                                                     unsigned short* __restrict__ w1T,
                                                     unsigned short* __restrict__ w2T,
                                                     int L) {
  int t = blockIdx.x;
  const float* src;
  unsigned short* dst;
  int R, C, dstOff;
  if (t < 576)       { src = Wq  + (size_t)L * 768 * 768;  R = 768;  C = 768;  dst = wqkvT; dstOff = 0;   }
  else if (t < 1728) { src = Wkv + (size_t)L * 768 * 1536; R = 768;  C = 1536; dst = wqkvT; dstOff = 768; t -= 576; }
  else if (t < 2304) { src = Wo  + (size_t)L * 768 * 768;  R = 768;  C = 768;  dst = woT;   dstOff = 0;   t -= 1728; }
  else if (t < 4608) { src = W1  + (size_t)L * 768 * 3072; R = 768;  C = 3072; dst = w1T;   dstOff = 0;   t -= 2304; }
  else               { src = W2  + (size_t)L * 3072 * 768; R = 3072; C = 768;  dst = w2T;   dstOff = 0;   t -= 4608; }
  int Ct = C >> 5;
  int bx = t % Ct, by = t / Ct;
  __shared__ float tt[32][33];
  int tx = threadIdx.x & 31, ty = threadIdx.x >> 5;  // ty 0..7
  int c0 = bx * 32, r0 = by * 32;
#pragma unroll
  for (int k = 0; k < 4; ++k) {
    int r = r0 + ty + k * 8;
    tt[ty + k * 8][tx] = src[(size_t)r * C + c0 + tx];
  }
  __syncthreads();
#pragma unroll
  for (int k = 0; k < 4; ++k) {
    int c = c0 + ty + k * 8;
    dst[(size_t)(dstOff + c) * R + r0 + tx] = f2bf(tt[tx][ty + k * 8]);
  }
}

// ---------------- V transpose: qkv[b,j,1536+g*64+d] -> vT[(b*12+g)*64+d][j] ----------------
__global__ __launch_bounds__(256) void transpose_v_kernel(const unsigned short* __restrict__ qkv,
                                                          unsigned short* __restrict__ vT) {
  __shared__ unsigned short t[32][33];
  int tx = threadIdx.x & 31, ty = threadIdx.x >> 5;
  int j0 = blockIdx.x * 32, d0 = blockIdx.y * 32;
  int bg = blockIdx.z;
  int b = bg / kH, g = bg % kH;
#pragma unroll
  for (int k = 0; k < 4; ++k) {
    int j = j0 + ty + k * 8;
    t[ty + k * 8][tx] = qkv[(size_t)(b * kN + j) * kQKV + 1536 + g * 64 + d0 + tx];
  }
  __syncthreads();
#pragma unroll
  for (int k = 0; k < 4; ++k) {
    int d = d0 + ty + k * 8;
    vT[((size_t)(b * kH + g) * kDh + d) * kN + j0 + tx] = t[tx][ty + k * 8];
  }
}

// ---------------- GEMM: A[M,lda]bf16 x Bt[N,lda]bf16 -> epilogue ----------------
// EPI 0: C=bf16 plain; EPI 1: bf16 gelu(acc+bias); EPI 2: resid += (acc+bias)*scl (single writer)
// EPI 3: split-K over blockIdx.z: atomicAdd(resid, (acc [+bias if z==0])*scl), K = per-split depth
template <int EPI>
__global__ __launch_bounds__(256) void gemm_kernel(const unsigned short* __restrict__ A,
                                                   const unsigned short* __restrict__ Bt,
                                                   const float* __restrict__ bias,
                                                   const float* __restrict__ scl,
                                                   float* __restrict__ resid,
                                                   unsigned short* __restrict__ C,
                                                   int K, int ldc, int lda) {
  __shared__ __align__(16) unsigned short lA[128 * 64];
  __shared__ __align__(16) unsigned short lB[128 * 64];
  int tid = threadIdx.x, wid = tid >> 6, lane = tid & 63;
  // XCD-aware bijective chunked swizzle (all grids have nwg % 8 == 0)
  int gx = gridDim.x;
  int nwg = gx * gridDim.y;
  int orig = blockIdx.y * gx + blockIdx.x;
  int chunk = nwg >> 3;
  int wg = (orig & 7) * chunk + (orig >> 3);
  int bx = wg % gx, by = wg / gx;
  int row0 = by * 128, col0 = bx * 128;
  int koff = (EPI == 3) ? blockIdx.z * K : 0;
  int wr = wid >> 1, wc = wid & 1;
  f32x4 zero = {0.f, 0.f, 0.f, 0.f};
  f32x4 acc[4][4];
#pragma unroll
  for (int m = 0; m < 4; ++m)
#pragma unroll
    for (int n = 0; n < 4; ++n) acc[m][n] = zero;

  for (int kt = 0; kt < K; kt += 64) {
    __syncthreads();
#pragma unroll
    for (int t = 0; t < 4; ++t) {
      int cbase = wid * 256 + t * 64;
      int c = cbase + lane;
      int r = c >> 3, slot = c & 7;
      int k8 = slot ^ (r & 7);  // source-swizzle so LDS holds XOR-swizzled layout
      gload_lds16(&A[(size_t)(row0 + r) * lda + koff + kt + k8 * 8], &lA[cbase * 8]);
      gload_lds16(&Bt[(size_t)(col0 + r) * lda + koff + kt + k8 * 8], &lB[cbase * 8]);
    }
    __syncthreads();
#pragma unroll
    for (int kk = 0; kk < 2; ++kk) {
      bf16x8 af[4], bfr[4];
      int kslot = kk * 4 + (lane >> 4);
#pragma unroll
      for (int m = 0; m < 4; ++m) {
        int r = wr * 64 + m * 16 + (lane & 15);
        af[m] = *reinterpret_cast<const bf16x8*>(&lA[r * 64 + ((kslot ^ (r & 7)) << 3)]);
      }
#pragma unroll
      for (int n = 0; n < 4; ++n) {
        int r = wc * 64 + n * 16 + (lane & 15);
        bfr[n] = *reinterpret_cast<const bf16x8*>(&lB[r * 64 + ((kslot ^ (r & 7)) << 3)]);
      }
#pragma unroll
      for (int m = 0; m < 4; ++m)
#pragma unroll
        for (int n = 0; n < 4; ++n) acc[m][n] = mfma16x16x32(af[m], bfr[n], acc[m][n]);
    }
  }
#pragma unroll
  for (int m = 0; m < 4; ++m)
#pragma unroll
    for (int n = 0; n < 4; ++n)
#pragma unroll
      for (int r4 = 0; r4 < 4; ++r4) {
        int row = row0 + wr * 64 + m * 16 + ((lane >> 4) << 2) + r4;
        int col = col0 + wc * 64 + n * 16 + (lane & 15);
        float v = acc[m][n][r4];
        if (EPI == 0) {
          C[(size_t)row * ldc + col] = f2bf(v);
        } else if (EPI == 1) {
          v += bias[col];
          v = 0.5f * v * (1.f + erff(v * 0.70710678118654752f));
          C[(size_t)row * ldc + col] = f2bf(v);
        } else if (EPI == 2) {
          v = (v + bias[col]) * scl[col];
          size_t idx = (size_t)row * kDim + col;
          resid[idx] = resid[idx] + v;
        } else {
          if (blockIdx.z == 0) v += bias[col];
          v *= scl[col];
          atomicAdd(&resid[(size_t)row * kDim + col], v);
        }
      }
}

// ---------------- QK^T raw per-head scores -> dots bf16, layout [b][i][j][h16] ----------------
// h slots 12..15 are zero. LDS-staged for fully coalesced dwordx4 global writes.
__global__ __launch_bounds__(256) void dots_kernel(const unsigned short* __restrict__ qkv,
                                                   unsigned short* __restrict__ dots,
                                                   int i0, int IC) {
  constexpr int TROW = 24;  // ushorts per (i,j) slot: 16 h + 8 pad (48B, 16B-aligned)
  __shared__ __align__(16) unsigned short T[32 * 32 * TROW];  // 48KB
  int tid = threadIdx.x, wid = tid >> 6, lane = tid & 63;
  int kg = lane >> 4, l15 = lane & 15;
  int j0 = blockIdx.x * 32;
  int il0 = blockIdx.y * 32;
  int b = blockIdx.z;
  // zero h-slots 12..15
  for (int idx = tid; idx < 2048; idx += 256) {
    int pos = idx >> 1;
    *(unsigned int*)&T[pos * TROW + 12 + (idx & 1) * 2] = 0u;
  }
  f32x4 zero = {0.f, 0.f, 0.f, 0.f};
#pragma unroll
  for (int rep = 0; rep < 3; ++rep) {
    int h = rep * 4 + wid;
    f32x4 acc[2][2];
    acc[0][0] = zero; acc[0][1] = zero; acc[1][0] = zero; acc[1][1] = zero;
#pragma unroll
    for (int kk = 0; kk < 2; ++kk) {
      bf16x8 aq[2], bk[2];
#pragma unroll
      for (int m = 0; m < 2; ++m) {
        int tok = i0 + il0 + m * 16 + l15;
        aq[m] = *reinterpret_cast<const bf16x8*>(
            &qkv[(size_t)(b * kN + tok) * kQKV + h * 64 + kk * 32 + kg * 8]);
      }
#pragma unroll
      for (int n = 0; n < 2; ++n) {
        int tj = j0 + n * 16 + l15;
        bk[n] = *reinterpret_cast<const bf16x8*>(
            &qkv[(size_t)(b * kN + tj) * kQKV + 768 + h * 64 + kk * 32 + kg * 8]);
      }
#pragma unroll
      for (int m = 0; m < 2; ++m)
#pragma unroll
        for (int n = 0; n < 2; ++n) acc[m][n] = mfma16x16x32(aq[m], bk[n], acc[m][n]);
    }
#pragma unroll
    for (int m = 0; m < 2; ++m)
#pragma unroll
      for (int n = 0; n < 2; ++n)
#pragma unroll
        for (int r = 0; r < 4; ++r)
          T[((m * 16 + kg * 4 + r) * 32 + n * 16 + l15) * TROW + h] = f2bf(acc[m][n][r]);
  }
  __syncthreads();
  // coalesced write-out: 2048 chunks of 16B
#pragma unroll
  for (int k = 0; k < 8; ++k) {
    int c = tid + k * 256;
    int pos = c >> 1, half = c & 1;
    int ii = pos >> 5, jj = pos & 31;
    *(f32x4*)&dots[((size_t)(b * IC + il0 + ii) * kN + j0 + jj) * 16 + half * 8] =
        *(const f32x4*)&T[pos * TROW + half * 8];
  }
}

// ---------------- Fused softmax+PV: premix MFMA + exp + postmix MFMA + PV MFMA ----------------
// Block = (16 local i-rows, b); two passes over dots (pass 2 L2-warm).
// E bounced through LDS stride-80B (bank-spread); P2 identical to validated round-8 layout.
__global__ __launch_bounds__(256) void softmax_pv_kernel(
    const unsigned short* __restrict__ dots,
    const float* __restrict__ pre, const float* __restrict__ post,
    const unsigned short* __restrict__ vT,
    unsigned short* __restrict__ attnout, int i0, int IC) {
  constexpr int EROW = 40;   // ushorts per E pos-row (80B)
  constexpr int PROW = 40;   // ushorts per P2 (g2,row) row (80B)
  __shared__ __align__(16) unsigned short E[512 * EROW];    // 40KB: [pos=ir*32+jj][g16]
  __shared__ __align__(16) unsigned short P2[192 * PROW];   // 15KB: [g2*16+row][j32]
  __shared__ __align__(16) unsigned short preA[16 * 32];
  __shared__ __align__(16) unsigned short postA[16 * 32];
  int tid = threadIdx.x, wid = tid >> 6, lane = tid & 63;
  int kg = lane >> 4, l15 = lane & 15;
  int itl = blockIdx.x * 16;   // local row base within chunk
  int b = blockIdx.y;

  for (int idx = tid; idx < 512; idx += 256) {
    int m = idx >> 5, k = idx & 31;
    bool in = (m < 12 && k < 12);
    preA[idx]  = f2bf(in ? pre[k * 12 + m] * 0.125f : 0.f);
    postA[idx] = f2bf(in ? post[k * 12 + m] : 0.f);
  }
  __syncthreads();
  bf16x8 preF  = *(const bf16x8*)&preA[l15 * 32 + kg * 8];   // A[g][h]
  bf16x8 postF = *(const bf16x8*)&postA[l15 * 32 + kg * 8];  // A[g2][g]
  f32x4 zero = {0.f, 0.f, 0.f, 0.f};
  bf16x8 zfrag = {0, 0, 0, 0, 0, 0, 0, 0};
  const unsigned short* dbase = dots + (size_t)b * IC * kN * 16;

  // ---- pass A: denominators (each wave owns 4 rows) ----
  float psum[4][4];
#pragma unroll
  for (int a = 0; a < 4; ++a)
#pragma unroll
    for (int r = 0; r < 4; ++r) psum[a][r] = 0.f;
#pragma unroll
  for (int a = 0; a < 4; ++a) {
    const unsigned short* dr = dbase + (size_t)(itl + wid * 4 + a) * kN * 16;
    for (int jg = 0; jg < 64; ++jg) {
      bf16x8 bfrag = (kg < 2) ? *(const bf16x8*)&dr[(jg * 16 + l15) * 16 + kg * 8] : zfrag;
      f32x4 d = mfma16x16x32(preF, bfrag, zero);  // D[g=kg*4+r][j=l15]
#pragma unroll
      for (int r = 0; r < 4; ++r) {
        float dc = fminf(fmaxf(d[r], -15.f), 15.f);
        psum[a][r] += (kg == 3) ? 0.f : __expf(dc);
      }
    }
  }
  float lgr[4][4];
#pragma unroll
  for (int a = 0; a < 4; ++a)
#pragma unroll
    for (int r = 0; r < 4; ++r) {
      float s = psum[a][r];
      s += __shfl_xor(s, 1); s += __shfl_xor(s, 2);
      s += __shfl_xor(s, 4); s += __shfl_xor(s, 8);
      lgr[a][r] = (kg < 3) ? (1.f / s) : 0.f;
    }

  // ---- pass B: E -> postmix -> PV per 32-j tile ----
  f32x4 pvacc[3][4];
#pragma unroll
  for (int gg = 0; gg < 3; ++gg)
#pragma unroll
    for (int n = 0; n < 4; ++n) pvacc[gg][n] = zero;
  int g2w = wid * 3;

  for (int t = 0; t < 32; ++t) {
    int j0 = t * 32;
    // premix + exp + normalize -> E (wave-exclusive pos rows: ir = wid*4+a)
#pragma unroll
    for (int a = 0; a < 4; ++a) {
      int ir = wid * 4 + a;
      const unsigned short* dr = dbase + (size_t)(itl + ir) * kN * 16;
#pragma unroll
      for (int jh = 0; jh < 2; ++jh) {
        bf16x8 bfrag = (kg < 2) ? *(const bf16x8*)&dr[(j0 + jh * 16 + l15) * 16 + kg * 8] : zfrag;
        f32x4 d = mfma16x16x32(preF, bfrag, zero);
        float pe[4];
#pragma unroll
        for (int r = 0; r < 4; ++r) {
          float dc = fminf(fmaxf(d[r], -15.f), 15.f);
          float ee = (kg == 3) ? 0.f : __expf(dc);
          pe[r] = ee * lgr[a][r];
        }
        unsigned int w0, w1;
        asm("v_cvt_pk_bf16_f32 %0, %1, %2" : "=v"(w0) : "v"(pe[0]), "v"(pe[1]));
        asm("v_cvt_pk_bf16_f32 %0, %1, %2" : "=v"(w1) : "v"(pe[2]), "v"(pe[3]));
        int pos = ir * 32 + jh * 16 + l15;
        *(unsigned int*)&E[pos * EROW + kg * 4] = w0;
        *(unsigned int*)&E[pos * EROW + kg * 4 + 2] = w1;
      }
    }
    __syncthreads();
    // postmix: 512 pos / 16 = 32 MFMAs, 8 per wave
#pragma unroll
    for (int pp = 0; pp < 8; ++pp) {
      int p = wid * 8 + pp;
      bf16x8 ef = (kg < 2) ? *(const bf16x8*)&E[(p * 16 + l15) * EROW + kg * 8] : zfrag;
      f32x4 d2 = mfma16x16x32(postF, ef, zero);  // D[g2=kg*4+r][pos=l15]
      if (kg < 3) {
        int pos = p * 16 + l15;
        int ir = pos >> 5, jj = pos & 31;
#pragma unroll
        for (int r = 0; r < 4; ++r)
          P2[((kg * 4 + r) * 16 + ir) * PROW + jj] = f2bf(d2[r]);
      }
    }
    __syncthreads();
    // PV: wave owns 3 g2; A[row=l15][k=j], B=vT
#pragma unroll
    for (int gg = 0; gg < 3; ++gg) {
      int g2 = g2w + gg;
      bf16x8 ap = *(const bf16x8*)&P2[(g2 * 16 + l15) * PROW + kg * 8];
#pragma unroll
      for (int n = 0; n < 4; ++n) {
        bf16x8 bv = *(const bf16x8*)&vT[((size_t)(b * kH + g2) * kDh + n * 16 + l15) * kN +
                                        j0 + kg * 8];
        pvacc[gg][n] = mfma16x16x32(ap, bv, pvacc[gg][n]);
      }
    }
    __syncthreads();
  }
#pragma unroll
  for (int gg = 0; gg < 3; ++gg)
#pragma unroll
    for (int n = 0; n < 4; ++n)
#pragma unroll
      for (int r = 0; r < 4; ++r) {
        int tok = i0 + itl + kg * 4 + r;
        int col = (g2w + gg) * 64 + n * 16 + l15;
        attnout[(size_t)(b * kN + tok) * kDim + col] = f2bf(pvacc[gg][n][r]);
      }
}

extern "C" void kernel_launch(void* const* d_in, const int* in_sizes, int n_in,
                              void* d_out, int out_size, void* d_ws, size_t ws_size,
                              hipStream_t stream) {
  (void)in_sizes; (void)n_in; (void)out_size;
  const float* x     = (const float*)d_in[0];
  const float* ln1_g = (const float*)d_in[1];
  const float* ln1_b = (const float*)d_in[2];
  const float* Wq    = (const float*)d_in[3];
  const float* Wkv   = (const float*)d_in[4];
  const float* pre   = (const float*)d_in[5];
  const float* post  = (const float*)d_in[6];
  const float* Wo    = (const float*)d_in[7];
  const float* bo    = (const float*)d_in[8];
  const float* s1    = (const float*)d_in[9];
  const float* ln2_g = (const float*)d_in[10];
  const float* ln2_b = (const float*)d_in[11];
  const float* W1    = (const float*)d_in[12];
  const float* b1    = (const float*)d_in[13];
  const float* W2    = (const float*)d_in[14];
  const float* b2    = (const float*)d_in[15];
  const float* s2    = (const float*)d_in[16];
  float* xo = (float*)d_out;

  char* ws = (char*)d_ws;
  size_t off = 0;
  auto alloc = [&](size_t bytes) -> void* {
    void* p = ws + off;
    off += (bytes + 255) & ~(size_t)255;
    return p;
  };
  unsigned short* h_buf   = (unsigned short*)alloc((size_t)kRows * kDim * 2);
  unsigned short* qkv     = (unsigned short*)alloc((size_t)kRows * kQKV * 2);
  unsigned short* vT      = (unsigned short*)alloc((size_t)kB * kH * kDh * kN * 2);
  unsigned short* attnout = (unsigned short*)alloc((size_t)kRows * kDim * 2);
  unsigned short* mid     = (unsigned short*)alloc((size_t)kRows * kMlp * 2);
  unsigned short* wqkvT   = (unsigned short*)alloc((size_t)kQKV * kDim * 2);
  unsigned short* woT     = (unsigned short*)alloc((size_t)kDim * kDim * 2);
  unsigned short* w1T     = (unsigned short*)alloc((size_t)kMlp * kDim * 2);
  unsigned short* w2T     = (unsigned short*)alloc((size_t)kDim * kMlp * 2);

  size_t base = off;
  // dots [b][i][j][h16] bf16: 8*IC*1024*16*2 bytes = IC*262144
  int IC = 1024;
  while (IC > 32 && base + (size_t)IC * 262144 + 1024 > ws_size) IC >>= 1;
  unsigned short* dots = (unsigned short*)alloc((size_t)kB * IC * kN * 16 * 2);

  hipMemcpyAsync(xo, x, (size_t)kRows * kDim * 4, hipMemcpyDeviceToDevice, stream);

  for (int L = 0; L < kDepth; ++L) {
    // --- attention block ---
    ln_kernel<<<kRows, 256, 0, stream>>>(xo, ln1_g + L * kDim, ln1_b + L * kDim, h_buf);
    transpose_all<<<6912, 256, 0, stream>>>(Wq, Wkv, Wo, W1, W2, wqkvT, woT, w1T, w2T, L);

    gemm_kernel<0><<<dim3(kQKV / 128, kRows / 128), 256, 0, stream>>>(
        h_buf, wqkvT, nullptr, nullptr, nullptr, qkv, kDim, kQKV, kDim);
    transpose_v_kernel<<<dim3(kN / 32, kDh / 32, kB * kH), 256, 0, stream>>>(qkv, vT);

    for (int i0 = 0; i0 < kN; i0 += IC) {
      dots_kernel<<<dim3(kN / 32, IC / 32, kB), 256, 0, stream>>>(qkv, dots, i0, IC);
      softmax_pv_kernel<<<dim3(IC / 16, kB), 256, 0, stream>>>(
          dots, pre + L * 144, post + L * 144, vT, attnout, i0, IC);
    }
    gemm_kernel<2><<<dim3(kDim / 128, kRows / 128), 256, 0, stream>>>(
        attnout, woT, bo + L * kDim, s1 + L * kDim, xo, nullptr, kDim, kDim, kDim);

    // --- MLP block ---
    ln_kernel<<<kRows, 256, 0, stream>>>(xo, ln2_g + L * kDim, ln2_b + L * kDim, h_buf);
    gemm_kernel<1><<<dim3(kMlp / 128, kRows / 128), 256, 0, stream>>>(
        h_buf, w1T, b1 + L * kMlp, nullptr, nullptr, mid, kDim, kMlp, kDim);
    gemm_kernel<3><<<dim3(kDim / 128, kRows / 128, 2), 256, 0, stream>>>(
        mid, w2T, b2 + L * kDim, s2 + L * kDim, xo, nullptr, kMlp / 2, kDim, kMlp);
  }
}

// Round 10
// 3995.037 us; speedup vs baseline: 2.0259x; 2.0259x over previous
//
#include <hip/hip_runtime.h>

constexpr int kDepth = 6;
constexpr int kB = 8;
constexpr int kN = 1024;
constexpr int kDim = 768;
constexpr int kH = 12;
constexpr int kDh = 64;
constexpr int kMlp = 3072;
constexpr int kRows = kB * kN;   // 8192
constexpr int kQKV = 2304;       // q(768) k(768) v(768)

typedef __attribute__((ext_vector_type(4))) float f32x4;
typedef __attribute__((ext_vector_type(8))) short bf16x8;

__device__ __forceinline__ f32x4 mfma16x16x32(bf16x8 a, bf16x8 b, f32x4 c) {
  return __builtin_amdgcn_mfma_f32_16x16x32_bf16(a, b, c, 0, 0, 0);
}

__device__ __forceinline__ unsigned short f2bf(float f) {
  unsigned int u = __builtin_bit_cast(unsigned int, f);
  u = u + 0x7FFFu + ((u >> 16) & 1u);
  return (unsigned short)(u >> 16);
}

__device__ __forceinline__ float bf2f(unsigned short u) {
  return __builtin_bit_cast(float, (unsigned int)u << 16);
}

__device__ __forceinline__ void gload_lds16(const void* g, void* l) {
  __builtin_amdgcn_global_load_lds((__attribute__((address_space(1))) void*)g,
                                   (__attribute__((address_space(3))) void*)l,
                                   16, 0, 0);
}

// ---------------- LayerNorm: f32 in -> bf16 out ----------------
__global__ __launch_bounds__(256) void ln_kernel(const float* __restrict__ x,
                                                 const float* __restrict__ gamma,
                                                 const float* __restrict__ beta,
                                                 unsigned short* __restrict__ out) {
  int row = blockIdx.x, tid = threadIdx.x;
  const float* xr = x + (size_t)row * kDim;
  float v0 = xr[tid], v1 = xr[tid + 256], v2 = xr[tid + 512];
  float s = v0 + v1 + v2;
  float q = v0 * v0 + v1 * v1 + v2 * v2;
#pragma unroll
  for (int o = 32; o >= 1; o >>= 1) {
    s += __shfl_xor(s, o);
    q += __shfl_xor(q, o);
  }
  __shared__ float ss[4], sq[4];
  int wid = tid >> 6, lane = tid & 63;
  if (lane == 0) { ss[wid] = s; sq[wid] = q; }
  __syncthreads();
  s = ss[0] + ss[1] + ss[2] + ss[3];
  q = sq[0] + sq[1] + sq[2] + sq[3];
  float mean = s * (1.0f / kDim);
  float var = q * (1.0f / kDim) - mean * mean;
  float rstd = rsqrtf(var + 1e-5f);
  unsigned short* orow = out + (size_t)row * kDim;
  orow[tid]       = f2bf((v0 - mean) * rstd * gamma[tid]       + beta[tid]);
  orow[tid + 256] = f2bf((v1 - mean) * rstd * gamma[tid + 256] + beta[tid + 256]);
  orow[tid + 512] = f2bf((v2 - mean) * rstd * gamma[tid + 512] + beta[tid + 512]);
}

// ---------------- Batched weight transpose: all 5 matrices of one layer ----------------
__global__ __launch_bounds__(256) void transpose_all(const float* __restrict__ Wq,
                                                     const float* __restrict__ Wkv,
                                                     const float* __restrict__ Wo,
                                                     const float* __restrict__ W1,
                                                     const float* __restrict__ W2,
                                                     unsigned short* __restrict__ wqkvT,
                                                     unsigned short* __restrict__ woT,
                                                     unsigned short* __restrict__ w1T,
                                                     unsigned short* __restrict__ w2T,
                                                     int L) {
  int t = blockIdx.x;
  const float* src;
  unsigned short* dst;
  int R, C, dstOff;
  if (t < 576)       { src = Wq  + (size_t)L * 768 * 768;  R = 768;  C = 768;  dst = wqkvT; dstOff = 0;   }
  else if (t < 1728) { src = Wkv + (size_t)L * 768 * 1536; R = 768;  C = 1536; dst = wqkvT; dstOff = 768; t -= 576; }
  else if (t < 2304) { src = Wo  + (size_t)L * 768 * 768;  R = 768;  C = 768;  dst = woT;   dstOff = 0;   t -= 1728; }
  else if (t < 4608) { src = W1  + (size_t)L * 768 * 3072; R = 768;  C = 3072; dst = w1T;   dstOff = 0;   t -= 2304; }
  else               { src = W2  + (size_t)L * 3072 * 768; R = 3072; C = 768;  dst = w2T;   dstOff = 0;   t -= 4608; }
  int Ct = C >> 5;
  int bx = t % Ct, by = t / Ct;
  __shared__ float tt[32][33];
  int tx = threadIdx.x & 31, ty = threadIdx.x >> 5;  // ty 0..7
  int c0 = bx * 32, r0 = by * 32;
#pragma unroll
  for (int k = 0; k < 4; ++k) {
    int r = r0 + ty + k * 8;
    tt[ty + k * 8][tx] = src[(size_t)r * C + c0 + tx];
  }
  __syncthreads();
#pragma unroll
  for (int k = 0; k < 4; ++k) {
    int c = c0 + ty + k * 8;
    dst[(size_t)(dstOff + c) * R + r0 + tx] = f2bf(tt[tx][ty + k * 8]);
  }
}

// ---------------- V transpose: qkv[b,j,1536+g*64+d] -> vT[(b*12+g)*64+d][j] ----------------
__global__ __launch_bounds__(256) void transpose_v_kernel(const unsigned short* __restrict__ qkv,
                                                          unsigned short* __restrict__ vT) {
  __shared__ unsigned short t[32][33];
  int tx = threadIdx.x & 31, ty = threadIdx.x >> 5;
  int j0 = blockIdx.x * 32, d0 = blockIdx.y * 32;
  int bg = blockIdx.z;
  int b = bg / kH, g = bg % kH;
#pragma unroll
  for (int k = 0; k < 4; ++k) {
    int j = j0 + ty + k * 8;
    t[ty + k * 8][tx] = qkv[(size_t)(b * kN + j) * kQKV + 1536 + g * 64 + d0 + tx];
  }
  __syncthreads();
#pragma unroll
  for (int k = 0; k < 4; ++k) {
    int d = d0 + ty + k * 8;
    vT[((size_t)(b * kH + g) * kDh + d) * kN + j0 + tx] = t[tx][ty + k * 8];
  }
}

// ---------------- GEMM: A[M,lda]bf16 x Bt[N,lda]bf16 -> epilogue ----------------
// EPI 0: C=bf16 plain; EPI 1: bf16 gelu(acc+bias); EPI 2: resid += (acc+bias)*scl
// EPI 3: split-K partials (plain f32 stores): resid[z][row][col] = acc
template <int EPI>
__global__ __launch_bounds__(256) void gemm_kernel(const unsigned short* __restrict__ A,
                                                   const unsigned short* __restrict__ Bt,
                                                   const float* __restrict__ bias,
                                                   const float* __restrict__ scl,
                                                   float* __restrict__ resid,
                                                   unsigned short* __restrict__ C,
                                                   int K, int ldc, int lda) {
  __shared__ __align__(16) unsigned short lA[128 * 64];
  __shared__ __align__(16) unsigned short lB[128 * 64];
  int tid = threadIdx.x, wid = tid >> 6, lane = tid & 63;
  // XCD-aware bijective chunked swizzle (all grids have nwg % 8 == 0)
  int gx = gridDim.x;
  int nwg = gx * gridDim.y;
  int orig = blockIdx.y * gx + blockIdx.x;
  int chunk = nwg >> 3;
  int wg = (orig & 7) * chunk + (orig >> 3);
  int bx = wg % gx, by = wg / gx;
  int row0 = by * 128, col0 = bx * 128;
  int koff = (EPI == 3) ? blockIdx.z * K : 0;
  int wr = wid >> 1, wc = wid & 1;
  f32x4 zero = {0.f, 0.f, 0.f, 0.f};
  f32x4 acc[4][4];
#pragma unroll
  for (int m = 0; m < 4; ++m)
#pragma unroll
    for (int n = 0; n < 4; ++n) acc[m][n] = zero;

  for (int kt = 0; kt < K; kt += 64) {
    __syncthreads();
#pragma unroll
    for (int t = 0; t < 4; ++t) {
      int cbase = wid * 256 + t * 64;
      int c = cbase + lane;
      int r = c >> 3, slot = c & 7;
      int k8 = slot ^ (r & 7);  // source-swizzle so LDS holds XOR-swizzled layout
      gload_lds16(&A[(size_t)(row0 + r) * lda + koff + kt + k8 * 8], &lA[cbase * 8]);
      gload_lds16(&Bt[(size_t)(col0 + r) * lda + koff + kt + k8 * 8], &lB[cbase * 8]);
    }
    __syncthreads();
#pragma unroll
    for (int kk = 0; kk < 2; ++kk) {
      bf16x8 af[4], bfr[4];
      int kslot = kk * 4 + (lane >> 4);
#pragma unroll
      for (int m = 0; m < 4; ++m) {
        int r = wr * 64 + m * 16 + (lane & 15);
        af[m] = *reinterpret_cast<const bf16x8*>(&lA[r * 64 + ((kslot ^ (r & 7)) << 3)]);
      }
#pragma unroll
      for (int n = 0; n < 4; ++n) {
        int r = wc * 64 + n * 16 + (lane & 15);
        bfr[n] = *reinterpret_cast<const bf16x8*>(&lB[r * 64 + ((kslot ^ (r & 7)) << 3)]);
      }
#pragma unroll
      for (int m = 0; m < 4; ++m)
#pragma unroll
        for (int n = 0; n < 4; ++n) acc[m][n] = mfma16x16x32(af[m], bfr[n], acc[m][n]);
    }
  }
#pragma unroll
  for (int m = 0; m < 4; ++m)
#pragma unroll
    for (int n = 0; n < 4; ++n)
#pragma unroll
      for (int r4 = 0; r4 < 4; ++r4) {
        int row = row0 + wr * 64 + m * 16 + ((lane >> 4) << 2) + r4;
        int col = col0 + wc * 64 + n * 16 + (lane & 15);
        float v = acc[m][n][r4];
        if (EPI == 0) {
          C[(size_t)row * ldc + col] = f2bf(v);
        } else if (EPI == 1) {
          v += bias[col];
          v = 0.5f * v * (1.f + erff(v * 0.70710678118654752f));
          C[(size_t)row * ldc + col] = f2bf(v);
        } else if (EPI == 2) {
          v = (v + bias[col]) * scl[col];
          size_t idx = (size_t)row * kDim + col;
          resid[idx] = resid[idx] + v;
        } else {
          resid[(size_t)blockIdx.z * kRows * kDim + (size_t)row * kDim + col] = v;
        }
      }
}

// ---------------- reduce W2 split-K partials: xo += (pw0 + pw1 + bias) * scl ----------------
__global__ __launch_bounds__(256) void reduce_w2(const float* __restrict__ pw,
                                                 const float* __restrict__ bias,
                                                 const float* __restrict__ scl,
                                                 float* __restrict__ xo) {
  int row = blockIdx.x, tid = threadIdx.x;
  const float* p0 = pw + (size_t)row * kDim;
  const float* p1 = pw + (size_t)kRows * kDim + (size_t)row * kDim;
  float* xr = xo + (size_t)row * kDim;
#pragma unroll
  for (int k = 0; k < 3; ++k) {
    int c = tid + k * 256;
    xr[c] = xr[c] + (p0[c] + p1[c] + bias[c]) * scl[c];
  }
}

// ---------------- QK^T raw per-head scores -> dots bf16, layout [b][i][j][h16] ----------------
// h slots 12..15 are zero. LDS-staged for fully coalesced dwordx4 global writes.
__global__ __launch_bounds__(256) void dots_kernel(const unsigned short* __restrict__ qkv,
                                                   unsigned short* __restrict__ dots,
                                                   int i0, int IC) {
  constexpr int TROW = 24;  // ushorts per (i,j) slot: 16 h + 8 pad (48B, 16B-aligned)
  __shared__ __align__(16) unsigned short T[32 * 32 * TROW];  // 48KB
  int tid = threadIdx.x, wid = tid >> 6, lane = tid & 63;
  int kg = lane >> 4, l15 = lane & 15;
  int j0 = blockIdx.x * 32;
  int il0 = blockIdx.y * 32;
  int b = blockIdx.z;
  // zero h-slots 12..15
  for (int idx = tid; idx < 2048; idx += 256) {
    int pos = idx >> 1;
    *(unsigned int*)&T[pos * TROW + 12 + (idx & 1) * 2] = 0u;
  }
  f32x4 zero = {0.f, 0.f, 0.f, 0.f};
#pragma unroll
  for (int rep = 0; rep < 3; ++rep) {
    int h = rep * 4 + wid;
    f32x4 acc[2][2];
    acc[0][0] = zero; acc[0][1] = zero; acc[1][0] = zero; acc[1][1] = zero;
#pragma unroll
    for (int kk = 0; kk < 2; ++kk) {
      bf16x8 aq[2], bk[2];
#pragma unroll
      for (int m = 0; m < 2; ++m) {
        int tok = i0 + il0 + m * 16 + l15;
        aq[m] = *reinterpret_cast<const bf16x8*>(
            &qkv[(size_t)(b * kN + tok) * kQKV + h * 64 + kk * 32 + kg * 8]);
      }
#pragma unroll
      for (int n = 0; n < 2; ++n) {
        int tj = j0 + n * 16 + l15;
        bk[n] = *reinterpret_cast<const bf16x8*>(
            &qkv[(size_t)(b * kN + tj) * kQKV + 768 + h * 64 + kk * 32 + kg * 8]);
      }
#pragma unroll
      for (int m = 0; m < 2; ++m)
#pragma unroll
        for (int n = 0; n < 2; ++n) acc[m][n] = mfma16x16x32(aq[m], bk[n], acc[m][n]);
    }
#pragma unroll
    for (int m = 0; m < 2; ++m)
#pragma unroll
      for (int n = 0; n < 2; ++n)
#pragma unroll
        for (int r = 0; r < 4; ++r)
          T[((m * 16 + kg * 4 + r) * 32 + n * 16 + l15) * TROW + h] = f2bf(acc[m][n][r]);
  }
  __syncthreads();
  // coalesced write-out: 2048 chunks of 16B
#pragma unroll
  for (int k = 0; k < 8; ++k) {
    int c = tid + k * 256;
    int pos = c >> 1, half = c & 1;
    int ii = pos >> 5, jj = pos & 31;
    *(f32x4*)&dots[((size_t)(b * IC + il0 + ii) * kN + j0 + jj) * 16 + half * 8] =
        *(const f32x4*)&T[pos * TROW + half * 8];
  }
}

// ---------------- MFMA premix + softmax (no-max+clamp) + MFMA postmix -> p bf16 ----------------
// dots layout [b][i][j][h16]; pbuf layout [b][g2][i][j] (unchanged for pv).
__global__ __launch_bounds__(256) void softmax_mix_kernel(const unsigned short* __restrict__ dots,
                                                          const float* __restrict__ pre,
                                                          const float* __restrict__ post,
                                                          unsigned short* __restrict__ pbuf,
                                                          int IC) {
  constexpr int EROW = 24;  // ushorts per j row of E (16 g + 8 pad, 16B-aligned)
  __shared__ __align__(16) unsigned short E[1024 * EROW];   // 48KB
  __shared__ __align__(16) unsigned short preA[16 * 32];
  __shared__ __align__(16) unsigned short postA[16 * 32];
  __shared__ float red[4][16];
  __shared__ float lgs[16];
  int tid = threadIdx.x, wid = tid >> 6, lane = tid & 63;
  int kg = lane >> 4, l15 = lane & 15;
  int i = blockIdx.x, b = blockIdx.y;
  // build preA[m=g][k=h] = pre[h][g] * 0.125, zero-padded
  for (int idx = tid; idx < 512; idx += 256) {
    int m = idx >> 5, k = idx & 31;
    preA[idx] = f2bf((m < 12 && k < 12) ? pre[k * 12 + m] * 0.125f : 0.f);
  }
  __syncthreads();
  bf16x8 preF = *(const bf16x8*)&preA[l15 * 32 + kg * 8];
  const unsigned short* drow = dots + (size_t)(b * IC + i) * kN * 16;
  f32x4 zero = {0.f, 0.f, 0.f, 0.f};
  bf16x8 zfrag = {0, 0, 0, 0, 0, 0, 0, 0};
  float psum[4] = {0.f, 0.f, 0.f, 0.f};
  // pass A: premix via MFMA, exp, stash E[j][g], accumulate psum
#pragma unroll
  for (int grp = 0; grp < 16; ++grp) {
    int j = wid * 256 + grp * 16 + l15;
    bf16x8 bfrag = (kg < 2) ? *(const bf16x8*)&drow[(size_t)j * 16 + kg * 8] : zfrag;
    f32x4 d = mfma16x16x32(preF, bfrag, zero);  // D[g=kg*4+r][j=l15]
    float ee[4];
#pragma unroll
    for (int r = 0; r < 4; ++r) {
      float dc = fminf(fmaxf(d[r], -15.f), 15.f);
      ee[r] = (kg == 3) ? 0.f : __expf(dc);
      psum[r] += ee[r];
    }
    unsigned int w0, w1;
    asm("v_cvt_pk_bf16_f32 %0, %1, %2" : "=v"(w0) : "v"(ee[0]), "v"(ee[1]));
    asm("v_cvt_pk_bf16_f32 %0, %1, %2" : "=v"(w1) : "v"(ee[2]), "v"(ee[3]));
    *(unsigned int*)&E[j * EROW + kg * 4] = w0;
    *(unsigned int*)&E[j * EROW + kg * 4 + 2] = w1;
  }
  // reduce psum over 16 cols (l15 lanes), then 4 waves
#pragma unroll
  for (int r = 0; r < 4; ++r) {
    psum[r] += __shfl_xor(psum[r], 1);
    psum[r] += __shfl_xor(psum[r], 2);
    psum[r] += __shfl_xor(psum[r], 4);
    psum[r] += __shfl_xor(psum[r], 8);
  }
  if (l15 == 0) {
#pragma unroll
    for (int r = 0; r < 4; ++r) red[wid][kg * 4 + r] = psum[r];
  }
  __syncthreads();
  if (tid < 16) {
    float s = red[0][tid] + red[1][tid] + red[2][tid] + red[3][tid];
    lgs[tid] = (tid < 12) ? 1.f / s : 0.f;
  }
  __syncthreads();
  // build postA[m=g2][k=g] = post[g][g2] * lg[g], zero-padded
  for (int idx = tid; idx < 512; idx += 256) {
    int m = idx >> 5, k = idx & 31;
    postA[idx] = f2bf((m < 12 && k < 12) ? post[k * 12 + m] * lgs[k] : 0.f);
  }
  __syncthreads();
  bf16x8 postF = *(const bf16x8*)&postA[l15 * 32 + kg * 8];
  // pass B: postmix via MFMA, write p
#pragma unroll
  for (int grp = 0; grp < 16; ++grp) {
    int j = wid * 256 + grp * 16 + l15;
    bf16x8 efrag = (kg < 2) ? *(const bf16x8*)&E[j * EROW + kg * 8] : zfrag;
    f32x4 d2 = mfma16x16x32(postF, efrag, zero);  // D[g2=kg*4+r][j=l15]
    if (kg < 3) {
#pragma unroll
      for (int r = 0; r < 4; ++r) {
        int g2 = kg * 4 + r;
        pbuf[((size_t)(b * kH + g2) * IC + i) * kN + j] = f2bf(d2[r]);
      }
    }
  }
}

// ---------------- PV: out[b,i,g*64+d] = sum_j p[b,g,i,j] * v[b,g,j,d] (32 i-rows/block) --------
__global__ __launch_bounds__(256) void pv_kernel(const unsigned short* __restrict__ pbuf,
                                                 const unsigned short* __restrict__ vT,
                                                 unsigned short* __restrict__ attn_out,
                                                 int i0, int IC) {
  int tid = threadIdx.x, wid = tid >> 6, lane = tid & 63;
  int kg = lane >> 4, l15 = lane & 15;
  int i32 = blockIdx.x * 32;
  int g = blockIdx.y, b = blockIdx.z;
  const unsigned short* prow = pbuf + (size_t)(b * kH + g) * IC * kN;
  const unsigned short* vrow = vT + (size_t)(b * kH + g) * kDh * kN;
  f32x4 zero = {0.f, 0.f, 0.f, 0.f};
  f32x4 acc[2][4];
#pragma unroll
  for (int half = 0; half < 2; ++half)
#pragma unroll
    for (int n = 0; n < 4; ++n) acc[half][n] = zero;
#pragma unroll
  for (int s = 0; s < 8; ++s) {
    int kt = (wid * 8 + s) * 32 + kg * 8;
    bf16x8 ap[2];
#pragma unroll
    for (int half = 0; half < 2; ++half)
      ap[half] = *reinterpret_cast<const bf16x8*>(&prow[(size_t)(i32 + half * 16 + l15) * kN + kt]);
#pragma unroll
    for (int n = 0; n < 4; ++n) {
      bf16x8 bv = *reinterpret_cast<const bf16x8*>(&vrow[(size_t)(n * 16 + l15) * kN + kt]);
#pragma unroll
      for (int half = 0; half < 2; ++half)
        acc[half][n] = mfma16x16x32(ap[half], bv, acc[half][n]);
    }
  }
  __shared__ float red[3][32][64];
  if (wid > 0) {
#pragma unroll
    for (int half = 0; half < 2; ++half)
#pragma unroll
      for (int n = 0; n < 4; ++n)
#pragma unroll
        for (int r = 0; r < 4; ++r)
          red[wid - 1][half * 16 + kg * 4 + r][n * 16 + l15] = acc[half][n][r];
  }
  __syncthreads();
  if (wid == 0) {
#pragma unroll
    for (int half = 0; half < 2; ++half)
#pragma unroll
      for (int n = 0; n < 4; ++n)
#pragma unroll
        for (int r = 0; r < 4; ++r) {
          int rr = half * 16 + kg * 4 + r, cc = n * 16 + l15;
          float v = acc[half][n][r] + red[0][rr][cc] + red[1][rr][cc] + red[2][rr][cc];
          int tok = i0 + i32 + rr;
          attn_out[(size_t)(b * kN + tok) * kDim + g * kDh + cc] = f2bf(v);
        }
  }
}

extern "C" void kernel_launch(void* const* d_in, const int* in_sizes, int n_in,
                              void* d_out, int out_size, void* d_ws, size_t ws_size,
                              hipStream_t stream) {
  (void)in_sizes; (void)n_in; (void)out_size;
  const float* x     = (const float*)d_in[0];
  const float* ln1_g = (const float*)d_in[1];
  const float* ln1_b = (const float*)d_in[2];
  const float* Wq    = (const float*)d_in[3];
  const float* Wkv   = (const float*)d_in[4];
  const float* pre   = (const float*)d_in[5];
  const float* post  = (const float*)d_in[6];
  const float* Wo    = (const float*)d_in[7];
  const float* bo    = (const float*)d_in[8];
  const float* s1    = (const float*)d_in[9];
  const float* ln2_g = (const float*)d_in[10];
  const float* ln2_b = (const float*)d_in[11];
  const float* W1    = (const float*)d_in[12];
  const float* b1    = (const float*)d_in[13];
  const float* W2    = (const float*)d_in[14];
  const float* b2    = (const float*)d_in[15];
  const float* s2    = (const float*)d_in[16];
  float* xo = (float*)d_out;

  char* ws = (char*)d_ws;
  size_t off = 0;
  auto alloc = [&](size_t bytes) -> void* {
    void* p = ws + off;
    off += (bytes + 255) & ~(size_t)255;
    return p;
  };
  unsigned short* h_buf   = (unsigned short*)alloc((size_t)kRows * kDim * 2);
  unsigned short* qkv     = (unsigned short*)alloc((size_t)kRows * kQKV * 2);
  unsigned short* vT      = (unsigned short*)alloc((size_t)kB * kH * kDh * kN * 2);
  unsigned short* attnout = (unsigned short*)alloc((size_t)kRows * kDim * 2);
  unsigned short* mid     = (unsigned short*)alloc((size_t)kRows * kMlp * 2);
  unsigned short* wqkvT   = (unsigned short*)alloc((size_t)kQKV * kDim * 2);
  unsigned short* woT     = (unsigned short*)alloc((size_t)kDim * kDim * 2);
  unsigned short* w1T     = (unsigned short*)alloc((size_t)kMlp * kDim * 2);
  unsigned short* w2T     = (unsigned short*)alloc((size_t)kDim * kMlp * 2);
  float* pw               = (float*)alloc((size_t)2 * kRows * kDim * 4);

  size_t base = off;
  // per-i-row bytes: dots [b][i][j][16] bf16 = 262144; pbuf [b][g2][i][j] = 196608
  int IC = 1024;
  while (IC > 32 && base + (size_t)IC * (262144 + 196608) + 1024 > ws_size) IC >>= 1;
  unsigned short* dots = (unsigned short*)alloc((size_t)kB * IC * kN * 16 * 2);
  unsigned short* pbuf = (unsigned short*)alloc((size_t)kB * kH * IC * kN * 2);

  hipMemcpyAsync(xo, x, (size_t)kRows * kDim * 4, hipMemcpyDeviceToDevice, stream);

  for (int L = 0; L < kDepth; ++L) {
    // --- attention block ---
    ln_kernel<<<kRows, 256, 0, stream>>>(xo, ln1_g + L * kDim, ln1_b + L * kDim, h_buf);
    transpose_all<<<6912, 256, 0, stream>>>(Wq, Wkv, Wo, W1, W2, wqkvT, woT, w1T, w2T, L);

    gemm_kernel<0><<<dim3(kQKV / 128, kRows / 128), 256, 0, stream>>>(
        h_buf, wqkvT, nullptr, nullptr, nullptr, qkv, kDim, kQKV, kDim);
    transpose_v_kernel<<<dim3(kN / 32, kDh / 32, kB * kH), 256, 0, stream>>>(qkv, vT);

    for (int i0 = 0; i0 < kN; i0 += IC) {
      dots_kernel<<<dim3(kN / 32, IC / 32, kB), 256, 0, stream>>>(qkv, dots, i0, IC);
      softmax_mix_kernel<<<dim3(IC, kB), 256, 0, stream>>>(
          dots, pre + L * 144, post + L * 144, pbuf, IC);
      pv_kernel<<<dim3(IC / 32, kH, kB), 256, 0, stream>>>(pbuf, vT, attnout, i0, IC);
    }
    gemm_kernel<2><<<dim3(kDim / 128, kRows / 128), 256, 0, stream>>>(
        attnout, woT, bo + L * kDim, s1 + L * kDim, xo, nullptr, kDim, kDim, kDim);

    // --- MLP block ---
    ln_kernel<<<kRows, 256, 0, stream>>>(xo, ln2_g + L * kDim, ln2_b + L * kDim, h_buf);
    gemm_kernel<1><<<dim3(kMlp / 128, kRows / 128), 256, 0, stream>>>(
        h_buf, w1T, b1 + L * kMlp, nullptr, nullptr, mid, kDim, kMlp, kDim);
    gemm_kernel<3><<<dim3(kDim / 128, kRows / 128, 2), 256, 0, stream>>>(
        mid, w2T, nullptr, nullptr, pw, nullptr, kMlp / 2, kDim, kMlp);
    reduce_w2<<<kRows, 256, 0, stream>>>(pw, b2 + L * kDim, s2 + L * kDim, xo);
  }
}